// Round 1
// baseline (490.500 us; speedup 1.0000x reference)
//
#include <hip/hip_runtime.h>

typedef unsigned short u16;
typedef unsigned int u32;
typedef __attribute__((ext_vector_type(8))) short bf16x8;
typedef __attribute__((ext_vector_type(4))) float f32x4;

__device__ __forceinline__ u16 f2bf(float f) {
  union { float f; u32 u; } v; v.f = f;
  u32 r = v.u + 0x7fffu + ((v.u >> 16) & 1u);  // RNE; inputs are finite
  return (u16)(r >> 16);
}

// ---------------- fp32 -> bf16 convert (vectorized) ----------------
__global__ void conv_bf16(const float* __restrict__ in, u16* __restrict__ out, int n) {
  int i = (blockIdx.x * 256 + threadIdx.x) * 4;
  if (i < n) {
    float4 v = *(const float4*)(in + i);
    ushort4 o;
    o.x = f2bf(v.x); o.y = f2bf(v.y); o.z = f2bf(v.z); o.w = f2bf(v.w);
    *(ushort4*)(out + i) = o;
  }
}

// ------------- W[K,N] fp32 -> T[N,K] bf16 (B-operand layout) -------------
__global__ void transpose_bf16(const float* __restrict__ W, u16* __restrict__ T,
                               int K, int N) {
  int k = blockIdx.x * 256 + threadIdx.x;  // coalesced write along k
  int n = blockIdx.y;
  T[(size_t)n * K + k] = f2bf(W[(size_t)k * N + n]);
}

// ---------------- bf16 GEMM: C[M,N] = A[M,K] * Bt[N,K]^T + bias ----------------
// mode 0: bf16 out, row=(b*2048+s), col=(h*64+d) -> [B,H,S,D]   (Q, K)
// mode 1: bf16 out transposed -> [B,H,D,S]                       (V)
// mode 2: fp32 out row-major [M,1024]                            (final)
__global__ __launch_bounds__(256, 2) void gemm_bf16(
    const u16* __restrict__ A, const u16* __restrict__ Bt,
    const float* __restrict__ bias, u16* __restrict__ outb,
    float* __restrict__ outf, int K, int mode) {
  __shared__ __align__(16) u16 lA[128 * 72];  // pad 64->72: 2-way bank alias (free)
  __shared__ __align__(16) u16 lB[128 * 72];
  const int tid = threadIdx.x;
  const int bm = blockIdx.x * 128;
  const int bn = blockIdx.y * 128;
  const int wid = tid >> 6, lane = tid & 63;
  const int wm = (wid >> 1) * 64, wn = (wid & 1) * 64;  // 2x2 waves of 64x64
  const int lrow = lane & 15, quad = lane >> 4;
  const int srow = tid >> 3, schk = tid & 7;
  f32x4 acc[4][4] = {};
  for (int k0 = 0; k0 < K; k0 += 64) {
#pragma unroll
    for (int rr = 0; rr < 128; rr += 32) {
      int r = srow + rr;
      *(uint4*)&lA[r * 72 + schk * 8] =
          *(const uint4*)(A + (size_t)(bm + r) * K + k0 + schk * 8);
      *(uint4*)&lB[r * 72 + schk * 8] =
          *(const uint4*)(Bt + (size_t)(bn + r) * K + k0 + schk * 8);
    }
    __syncthreads();
#pragma unroll
    for (int ks = 0; ks < 2; ks++) {
      bf16x8 af[4], bfr[4];
#pragma unroll
      for (int i = 0; i < 4; i++)
        af[i] = *(const bf16x8*)&lA[(wm + i * 16 + lrow) * 72 + ks * 32 + quad * 8];
#pragma unroll
      for (int j = 0; j < 4; j++)
        bfr[j] = *(const bf16x8*)&lB[(wn + j * 16 + lrow) * 72 + ks * 32 + quad * 8];
#pragma unroll
      for (int i = 0; i < 4; i++)
#pragma unroll
        for (int j = 0; j < 4; j++)
          acc[i][j] = __builtin_amdgcn_mfma_f32_16x16x32_bf16(af[i], bfr[j], acc[i][j], 0, 0, 0);
    }
    __syncthreads();
  }
  // epilogue: C row = quad*4+reg, col = lane&15 (verified C/D layout)
#pragma unroll
  for (int i = 0; i < 4; i++)
#pragma unroll
    for (int j = 0; j < 4; j++)
#pragma unroll
      for (int r = 0; r < 4; r++) {
        int row = bm + wm + i * 16 + quad * 4 + r;
        int col = bn + wn + j * 16 + lrow;
        float v = acc[i][j][r] + bias[col];
        if (mode == 2) {
          outf[(size_t)row * 1024 + col] = v;
        } else {
          int b = row >> 11, s = row & 2047;
          int h = col >> 6, d = col & 63;
          size_t idx = (mode == 0)
              ? ((size_t)(b * 16 + h) * 2048 + s) * 64 + d
              : ((size_t)(b * 16 + h) * 64 + d) * 2048 + s;
          outb[idx] = f2bf(v);
        }
      }
}

// ---------------- flash attention: per (b*16+h, qtile of 64) ----------------
// Q,K: [BH, 2048, 64] bf16; Vt: [BH, 64, 2048] bf16; ctx out: [8192, 1024] bf16
__global__ __launch_bounds__(256, 2) void flash_attn(
    const u16* __restrict__ Q, const u16* __restrict__ Kt,
    const u16* __restrict__ Vt, u16* __restrict__ ctx) {
  __shared__ __align__(16) u16 lK[128 * 72];      // [kv=128][d=64 pad 72]
  __shared__ __align__(16) u16 lV[64 * 136];      // [d=64][kv=128 pad 136]
  __shared__ __align__(16) u16 lP[4][16 * 136];   // per-wave P tile [q=16][kv pad 136]
  const int bh = blockIdx.x;
  const int q0 = blockIdx.y * 64;
  const int tid = threadIdx.x, wid = tid >> 6, lane = tid & 63;
  const int lrow = lane & 15, quad = lane >> 4;
  const size_t base = (size_t)bh * 2048 * 64;
  // Q A-fragments live in registers for the whole block (wave owns 16 q-rows)
  bf16x8 qf[2];
#pragma unroll
  for (int ks = 0; ks < 2; ks++)
    qf[ks] = *(const bf16x8*)(Q + base + (size_t)(q0 + wid * 16 + lrow) * 64 + ks * 32 + quad * 8);
  f32x4 of[4] = {};
  float m_i[4], l_i[4];
#pragma unroll
  for (int r = 0; r < 4; r++) { m_i[r] = -1e30f; l_i[r] = 0.f; }
  const int srow = tid >> 3, schk = tid & 7;
  const int vrow = tid >> 4, vchk = tid & 15;
  for (int kv0 = 0; kv0 < 2048; kv0 += 128) {
    __syncthreads();  // prev iter's lK/lV reads done
#pragma unroll
    for (int rr = 0; rr < 128; rr += 32) {
      int r = srow + rr;
      *(uint4*)&lK[r * 72 + schk * 8] =
          *(const uint4*)(Kt + base + (size_t)(kv0 + r) * 64 + schk * 8);
    }
#pragma unroll
    for (int rr = 0; rr < 64; rr += 16) {
      int r = vrow + rr;
      *(uint4*)&lV[r * 136 + vchk * 8] =
          *(const uint4*)(Vt + base + (size_t)r * 2048 + kv0 + vchk * 8);
    }
    __syncthreads();
    // S = Q K^T  (16 q-rows x 128 kv per wave)
    f32x4 sf[8];
#pragma unroll
    for (int n = 0; n < 8; n++) {
      bf16x8 k0f = *(const bf16x8*)&lK[(n * 16 + lrow) * 72 + quad * 8];
      bf16x8 k1f = *(const bf16x8*)&lK[(n * 16 + lrow) * 72 + 32 + quad * 8];
      f32x4 s = {};
      s = __builtin_amdgcn_mfma_f32_16x16x32_bf16(qf[0], k0f, s, 0, 0, 0);
      s = __builtin_amdgcn_mfma_f32_16x16x32_bf16(qf[1], k1f, s, 0, 0, 0);
      sf[n] = s;
    }
    // online softmax, per C-layout row r (row = quad*4+r); shuffles with mask<16
    // stay inside the 16-lane group that shares a row
    float alpha[4];
#pragma unroll
    for (int r = 0; r < 4; r++) {
      float mx = sf[0][r];
#pragma unroll
      for (int n = 1; n < 8; n++) mx = fmaxf(mx, sf[n][r]);
#pragma unroll
      for (int off = 1; off < 16; off <<= 1) mx = fmaxf(mx, __shfl_xor(mx, off, 64));
      mx *= 0.125f;  // 1/sqrt(64); scale after max (monotone, scale>0)
      float mn = fmaxf(m_i[r], mx);
      alpha[r] = __expf(m_i[r] - mn);
      m_i[r] = mn;
      float rs = 0.f;
#pragma unroll
      for (int n = 0; n < 8; n++) {
        float p = __expf(sf[n][r] * 0.125f - mn);
        sf[n][r] = p;
        rs += p;
      }
#pragma unroll
      for (int off = 1; off < 16; off <<= 1) rs += __shfl_xor(rs, off, 64);
      l_i[r] = l_i[r] * alpha[r] + rs;
#pragma unroll
      for (int n = 0; n < 4; n++) of[n][r] *= alpha[r];
    }
    // P -> LDS (C-layout regs -> A-operand layout), m120-verified round trip
#pragma unroll
    for (int n = 0; n < 8; n++)
#pragma unroll
      for (int r = 0; r < 4; r++)
        lP[wid][(quad * 4 + r) * 136 + n * 16 + lrow] = f2bf(sf[n][r]);
    __syncthreads();  // order cross-lane P write->read (and cheap)
    // O += P @ V
#pragma unroll
    for (int kstep = 0; kstep < 4; kstep++) {
      bf16x8 pf = *(const bf16x8*)&lP[wid][lrow * 136 + kstep * 32 + quad * 8];
#pragma unroll
      for (int n = 0; n < 4; n++) {
        bf16x8 vf = *(const bf16x8*)&lV[(n * 16 + lrow) * 136 + kstep * 32 + quad * 8];
        of[n] = __builtin_amdgcn_mfma_f32_16x16x32_bf16(pf, vf, of[n], 0, 0, 0);
      }
    }
  }
  // epilogue: ctx[b*2048+q][h*64+d] bf16
  const int b = bh >> 4, h = bh & 15;
#pragma unroll
  for (int n = 0; n < 4; n++)
#pragma unroll
    for (int r = 0; r < 4; r++) {
      int row = q0 + wid * 16 + quad * 4 + r;
      int col = h * 64 + n * 16 + lrow;
      float v = of[n][r] / l_i[r];
      ctx[((size_t)b * 2048 + row) * 1024 + col] = f2bf(v);
    }
}

extern "C" void kernel_launch(void* const* d_in, const int* in_sizes, int n_in,
                              void* d_out, int out_size, void* d_ws, size_t ws_size,
                              hipStream_t stream) {
  const float* query = (const float*)d_in[0];
  const float* key   = (const float*)d_in[1];
  const float* value = (const float*)d_in[2];
  const float* Wq = (const float*)d_in[3];
  const float* bq = (const float*)d_in[4];
  const float* Wk = (const float*)d_in[5];
  const float* bk = (const float*)d_in[6];
  const float* Wv = (const float*)d_in[7];
  const float* bv = (const float*)d_in[8];
  const float* Wo = (const float*)d_in[9];
  const float* bo = (const float*)d_in[10];
  float* out = (float*)d_out;
  char* ws = (char*)d_ws;

  const size_t SZ_QKV = (size_t)8192 * 1024 * 2;  // 16 MiB per bf16 [8192,1024]
  const size_t SZ_KIN = (size_t)8192 * 768 * 2;
  u16* q_ws  = (u16*)(ws);                        // [B,H,2048,64]
  u16* k_ws  = (u16*)(ws + SZ_QKV);               // [B,H,2048,64]
  u16* vt_ws = (u16*)(ws + 2 * SZ_QKV);           // [B,H,64,2048]
  u16* qin   = (u16*)(ws + 3 * SZ_QKV);           // query bf16 [8192,1024]
  u16* kin   = (u16*)(ws + 4 * SZ_QKV);           // key   bf16 [8192,768]
  u16* vin   = (u16*)(ws + 4 * SZ_QKV + SZ_KIN);  // value bf16 [8192,768]
  u16* ctx   = qin;  // alias: qin dead after Q projection; same size
  u16* wq_t  = (u16*)(ws + 4 * SZ_QKV + 2 * SZ_KIN);
  u16* wk_t  = wq_t + 1024 * 1024;
  u16* wv_t  = wk_t + 1024 * 768;
  u16* wo_t  = wv_t + 1024 * 768;
  // total ws: ~99 MB

  conv_bf16<<<8192, 256, 0, stream>>>(query, qin, 8388608);
  conv_bf16<<<6144, 256, 0, stream>>>(key, kin, 6291456);
  conv_bf16<<<6144, 256, 0, stream>>>(value, vin, 6291456);
  transpose_bf16<<<dim3(4, 1024), 256, 0, stream>>>(Wq, wq_t, 1024, 1024);
  transpose_bf16<<<dim3(3, 1024), 256, 0, stream>>>(Wk, wk_t, 768, 1024);
  transpose_bf16<<<dim3(3, 1024), 256, 0, stream>>>(Wv, wv_t, 768, 1024);
  transpose_bf16<<<dim3(4, 1024), 256, 0, stream>>>(Wo, wo_t, 1024, 1024);

  gemm_bf16<<<dim3(64, 8), 256, 0, stream>>>(qin, wq_t, bq, q_ws, nullptr, 1024, 0);
  gemm_bf16<<<dim3(64, 8), 256, 0, stream>>>(kin, wk_t, bk, k_ws, nullptr, 768, 0);
  gemm_bf16<<<dim3(64, 8), 256, 0, stream>>>(vin, wv_t, bv, vt_ws, nullptr, 768, 1);

  flash_attn<<<dim3(64, 32), 256, 0, stream>>>(q_ws, k_ws, vt_ws, ctx);

  gemm_bf16<<<dim3(64, 8), 256, 0, stream>>>(ctx, wo_t, bo, nullptr, out, 1024, 2);
}